// Round 12
// baseline (162.690 us; speedup 1.0000x reference)
//
#include <hip/hip_runtime.h>
#include <hip/hip_bf16.h>
#include <math.h>

// GCN 2-layer: x[N,128] @ W1[128,128] -> gather/scatter norm agg -> +b1,relu
//              -> @ W2[128,64] -> agg -> +b2 -> log_softmax
// N=50000, E=1,600,000 (+N self loops handled analytically)
// - GEMMs: bf16 MFMA (16x16x32), XOR-swizzled LDS, W pre-transposed to bf16.
// - Gather tables store PRE-SCALED messages t[s] = dinv[s]*(xW)[s] in fp8 e4m3.
// - agg1 table split into two dense 64-ch halves [2][N][64] (3.2MB/pass -> fits
//   4MB per-XCD L2); agg2 table [N][64] already fits. Full-wave 4-rows/instr
//   gathers (16-lane groups x 4ch), csr broadcast via shfl + prefetch.
// - Graph build with zero per-edge global atomics (LDS-histogram binning).

typedef unsigned int uint;
typedef unsigned short ushort_t;
typedef unsigned char uchar_t;
typedef __attribute__((ext_vector_type(8))) short bf16x8;
typedef __attribute__((ext_vector_type(4))) float f32x4;
typedef __attribute__((ext_vector_type(2))) float f32x2;

#define BSH 7                    // bucket shift: 128 nodes per bucket
#define NBMAX 400                // >= ceil(50000/128)=391
#define BIN_CHUNK 4096           // edges per k_bin block (391 blocks)
#define CAP 6144                 // bin capacity per bucket (expected 4092, sd ~64)

__device__ inline ushort_t f2b(float f) {
    uint u = __float_as_uint(f);
    return (ushort_t)((u + 0x7fffu + ((u >> 16) & 1u)) >> 16);   // RNE
}

// ---- fp8 e4m3fn encode (RNE) / decode: manual fallbacks ----
__device__ inline uchar_t f2e4m3_sw(float f) {
    float a = fabsf(f);
    a = fminf(a, 448.f);
    uint sign = (__float_as_uint(f) >> 24) & 0x80u;
    uint u = __float_as_uint(a);
    int e = (int)(u >> 23) - 127;
    uint code;
    if (e < -6) {
        float t = a * 512.0f;
        uint m = (uint)(t + 0.5f);
        code = (m > 7) ? 0x08u : m;
    } else {
        uint lsb = (u >> 20) & 1u;
        u += 0x0007FFFFu + lsb;
        e = (int)(u >> 23) - 127;
        if (e > 8) code = 0x7Eu;
        else code = ((uint)(e + 7) << 3) | ((u >> 20) & 7u);
    }
    return (uchar_t)(sign | code);
}
__device__ inline float e4m3_sw(uint c) {
    uint ef = (c >> 3) & 15u, m = c & 7u;
    float v = ef ? __uint_as_float(((ef + 120u) << 23) | (m << 20))
                 : (float)m * 0.001953125f;
    return (c & 0x80u) ? -v : v;
}

// ---- hw fp8 conversions (gfx940+; OCP e4m3fn on gfx950) with sw fallback ----
__device__ inline f32x2 fp8x2_lo(uint v) {            // decode bytes 0,1
#if __has_builtin(__builtin_amdgcn_cvt_pk_f32_fp8)
    return __builtin_amdgcn_cvt_pk_f32_fp8(v, false);
#else
    return (f32x2){e4m3_sw(v & 255u), e4m3_sw((v >> 8) & 255u)};
#endif
}
__device__ inline f32x2 fp8x2_hi(uint v) {            // decode bytes 2,3
#if __has_builtin(__builtin_amdgcn_cvt_pk_f32_fp8)
    return __builtin_amdgcn_cvt_pk_f32_fp8(v, true);
#else
    return (f32x2){e4m3_sw((v >> 16) & 255u), e4m3_sw((v >> 24) & 255u)};
#endif
}
__device__ inline uchar_t f32_fp8(float f) {          // encode (RNE)
#if __has_builtin(__builtin_amdgcn_cvt_pk_fp8_f32)
    return (uchar_t)(__builtin_amdgcn_cvt_pk_fp8_f32(f, f, 0u, false) & 0xffu);
#else
    return f2e4m3_sw(f);
#endif
}

// ---------------- init: zero bucket counters ----------------
__global__ __launch_bounds__(256) void k_init(int* __restrict__ bktcnt, int nbk) {
    int i = blockIdx.x * 256 + threadIdx.x;
    if (i < nbk) bktcnt[i] = 0;
}

// ---------------- bin: bucket edges by dst>>BSH (LDS hist; block-segment writes) ----------------
__global__ __launch_bounds__(256) void k_bin(const int* __restrict__ esrc, const int* __restrict__ edst,
                                             int* __restrict__ bktcnt, uint* __restrict__ bin,
                                             int e, int nbk) {
    __shared__ int hist[NBMAX];
    __shared__ int segbase[NBMAX];
    int tid = threadIdx.x;
    int b0 = blockIdx.x * BIN_CHUNK;
    int b1 = min(b0 + BIN_CHUNK, e);
    for (int i = tid; i < nbk; i += 256) hist[i] = 0;
    __syncthreads();
    for (int i = b0 + tid * 4; i < b1; i += 1024) {
        if (i + 4 <= b1) {
            int4 d = *(const int4*)&edst[i];
            atomicAdd(&hist[d.x >> BSH], 1);
            atomicAdd(&hist[d.y >> BSH], 1);
            atomicAdd(&hist[d.z >> BSH], 1);
            atomicAdd(&hist[d.w >> BSH], 1);
        } else {
            for (int j = i; j < b1; ++j) atomicAdd(&hist[edst[j] >> BSH], 1);
        }
    }
    __syncthreads();
    for (int b = tid; b < nbk; b += 256) {
        int c = hist[b];
        int gb = c ? atomicAdd(&bktcnt[b], c) : 0;
        segbase[b] = b * CAP + gb;
        hist[b] = 0;  // reuse as local cursor
    }
    __syncthreads();
    for (int i = b0 + tid * 4; i < b1; i += 1024) {
        if (i + 4 <= b1) {
            int4 d = *(const int4*)&edst[i];
            int4 s = *(const int4*)&esrc[i];
            int bx = d.x >> BSH, by = d.y >> BSH, bz = d.z >> BSH, bw = d.w >> BSH;
            int px = atomicAdd(&hist[bx], 1);
            int py = atomicAdd(&hist[by], 1);
            int pz = atomicAdd(&hist[bz], 1);
            int pw = atomicAdd(&hist[bw], 1);
            bin[segbase[bx] + px] = (uint)s.x | ((uint)(d.x & 127) << 17);
            bin[segbase[by] + py] = (uint)s.y | ((uint)(d.y & 127) << 17);
            bin[segbase[bz] + pz] = (uint)s.z | ((uint)(d.z & 127) << 17);
            bin[segbase[bw] + pw] = (uint)s.w | ((uint)(d.w & 127) << 17);
        } else {
            for (int j = i; j < b1; ++j) {
                int d = edst[j], s = esrc[j];
                int b = d >> BSH;
                int p = atomicAdd(&hist[b], 1);
                bin[segbase[b] + p] = (uint)s | ((uint)(d & 127) << 17);
            }
        }
    }
}

// ---------------- scan of 391 bucket counts -> bucket CSR bases (one block) ----------------
__global__ __launch_bounds__(512) void k_scanBkt(const int* __restrict__ bktcnt, int* __restrict__ bktoff,
                                                 int nbk) {
    int tid = threadIdx.x;
    int v = (tid < nbk) ? bktcnt[tid] : 0;
    int x = v;
    for (int off = 1; off < 64; off <<= 1) {
        int y = __shfl_up(x, off);
        if ((tid & 63) >= off) x += y;
    }
    __shared__ int wt[8];
    if ((tid & 63) == 63) wt[tid >> 6] = x;
    __syncthreads();
    int w = tid >> 6, woff = 0;
    for (int k = 0; k < w; ++k) woff += wt[k];
    if (tid < nbk) bktoff[tid] = x - v + woff;
}

// ---------------- per-bucket: count/scan/scatter inside an L2-resident window ----------------
__global__ __launch_bounds__(256) void k_bucket(const uint* __restrict__ bin, const int* __restrict__ bktcnt,
                                                const int* __restrict__ bktoff,
                                                int* __restrict__ rowstart, int* __restrict__ cnt,
                                                float* __restrict__ dinv, int* __restrict__ csr, int n) {
    __shared__ int lcnt[1 << BSH];
    __shared__ int cur[1 << BSH];
    __shared__ int wt[4];
    int b = blockIdx.x;
    int tid = threadIdx.x;
    int lo = b << BSH;
    int nl = min(1 << BSH, n - lo);
    int m = bktcnt[b];
    int base = b * CAP;
    int obase = bktoff[b];
    if (tid < (1 << BSH)) lcnt[tid] = 0;
    __syncthreads();
    for (int i = tid; i < m; i += 256) {
        uint v = bin[base + i];
        atomicAdd(&lcnt[v >> 17], 1);
    }
    __syncthreads();
    int v = (tid < (1 << BSH)) ? lcnt[tid] : 0;
    int x = v;
    for (int off = 1; off < 64; off <<= 1) {
        int y = __shfl_up(x, off);
        if ((tid & 63) >= off) x += y;
    }
    if ((tid & 63) == 63) wt[tid >> 6] = x;
    __syncthreads();
    int excl = x - v + ((tid >= 64 && tid < 128) ? wt[0] : 0);
    if (tid < nl) {
        int node = lo + tid;
        rowstart[node] = obase + excl;
        cnt[node] = v;
        dinv[node] = rsqrtf((float)(v + 1));   // +1 self loop
        cur[tid] = obase + excl;
    }
    __syncthreads();
    for (int i = tid; i < m; i += 256) {
        uint en = bin[base + i];
        int dl = en >> 17;
        int p = atomicAdd(&cur[dl], 1);
        csr[p] = (int)(en & 0x1FFFFu);
    }
}

// ---------------- one-time weight transpose+cvt: W1[128x128]->W1t[n][k], W2[128x64]->W2t[n][k] ----
__global__ __launch_bounds__(256) void k_cvtW(const float* __restrict__ W1, const float* __restrict__ W2,
                                              ushort_t* __restrict__ W1t, ushort_t* __restrict__ W2t) {
    int i = blockIdx.x * 256 + threadIdx.x;
    if (i < 16384) {
        int k = i >> 7, nn = i & 127;
        W1t[nn * 128 + k] = f2b(W1[k * 128 + nn]);
    } else if (i < 16384 + 8192) {
        int j = i - 16384;
        int k = j >> 6, nn = j & 63;
        W2t[nn * 128 + k] = f2b(W2[k * 64 + nn]);
    }
}

// ---------------- MFMA bf16 GEMM: Y[n,COLS] = dinv[row] * (X[n,128] @ W[128,COLS]) -------------
// BR=64 rows/block, 4 waves x 16 rows; full K=128 in LDS; Wt = W^T[n][k] bf16.
// OUTFP8: emit fp8 e4m3 of the dinv-prescaled value (gather-table form).
// OUTSPLIT: write fp8 output as two dense halves [ch>>6][row][ch&63].
template <int COLS, bool XBF16, bool OUTFP8, bool OUTSPLIT>
__global__ __launch_bounds__(256) void k_mgemm(const void* __restrict__ Xv, const ushort_t* __restrict__ Wt,
                                               const float* __restrict__ dinv,
                                               void* __restrict__ Yv, int nrows) {
    constexpr int NT = COLS / 16;                  // col tiles
    __shared__ ushort_t lsX[64 * 128];             // 16KB
    __shared__ ushort_t lsW[COLS * 128];           // 32KB (COLS=128) / 16KB (64)
    int tid = threadIdx.x;
    int rbase = blockIdx.x * 64;

    // stage X tile: 8192 bf16, 8 per thread-iter, swizzled 16B stores
#pragma unroll
    for (int it = 0; it < 4; ++it) {
        int idx = (tid + it * 256) * 8;
        int r = idx >> 7, c = idx & 127;
        int grow = rbase + r;
        uint4 pv = make_uint4(0, 0, 0, 0);
        if (grow < nrows) {
            if (XBF16) {
                pv = *(const uint4*)((const ushort_t*)Xv + (size_t)grow * 128 + c);
            } else {
                const float* xp = (const float*)Xv + (size_t)grow * 128 + c;
                float4 a = *(const float4*)xp;
                float4 b = *(const float4*)(xp + 4);
                pv.x = (uint)f2b(a.x) | ((uint)f2b(a.y) << 16);
                pv.y = (uint)f2b(a.z) | ((uint)f2b(a.w) << 16);
                pv.z = (uint)f2b(b.x) | ((uint)f2b(b.y) << 16);
                pv.w = (uint)f2b(b.z) | ((uint)f2b(b.w) << 16);
            }
        }
        int boff = (r * 256 + c * 2) ^ ((r & 7) << 4);
        *(uint4*)((char*)lsX + boff) = pv;
    }
    // stage W^T: COLS*128 bf16 contiguous from global, swizzled
#pragma unroll
    for (int it = 0; it < NT; ++it) {
        int idx = (tid + it * 256) * 8;
        int nr = idx >> 7, k = idx & 127;
        uint4 v = *(const uint4*)&Wt[nr * 128 + k];
        int boff = (nr * 256 + k * 2) ^ ((nr & 7) << 4);
        *(uint4*)((char*)lsW + boff) = v;
    }
    __syncthreads();

    int w = tid >> 6, l = tid & 63;
    int lr = l & 15, lg = l >> 4;
    int xrow = w * 16 + lr;
    bf16x8 a[4];
#pragma unroll
    for (int ks = 0; ks < 4; ++ks) {
        int boff = (xrow * 256 + (ks * 32 + lg * 8) * 2) ^ ((xrow & 7) << 4);
        a[ks] = *(const bf16x8*)((const char*)lsX + boff);
    }
    f32x4 acc[NT];
#pragma unroll
    for (int ct = 0; ct < NT; ++ct) {
        acc[ct] = (f32x4){0.f, 0.f, 0.f, 0.f};
#pragma unroll
        for (int ks = 0; ks < 4; ++ks) {
            int wrow = ct * 16 + lr;
            int boff = (wrow * 256 + (ks * 32 + lg * 8) * 2) ^ ((wrow & 7) << 4);
            bf16x8 b = *(const bf16x8*)((const char*)lsW + boff);
            acc[ct] = __builtin_amdgcn_mfma_f32_16x16x32_bf16(a[ks], b, acc[ct], 0, 0, 0);
        }
    }
    // per-output-row dinv prescale (rows depend on r only)
    float dr[4];
#pragma unroll
    for (int r = 0; r < 4; ++r) {
        int row = rbase + w * 16 + lg * 4 + r;
        dr[r] = (OUTFP8 && row < nrows) ? dinv[row] : 1.f;
    }
    // C-write: row = rbase + w*16 + lg*4 + r, ch = ct*16 + lr  [m89 layout]
#pragma unroll
    for (int ct = 0; ct < NT; ++ct) {
        int ch = ct * 16 + lr;
#pragma unroll
        for (int r = 0; r < 4; ++r) {
            int row = rbase + w * 16 + lg * 4 + r;
            if (row < nrows) {
                if (OUTFP8) {
                    size_t addr = OUTSPLIT
                        ? (size_t)(ch >> 6) * ((size_t)nrows * 64) + (size_t)row * 64 + (ch & 63)
                        : (size_t)row * COLS + ch;
                    ((uchar_t*)Yv)[addr] = f32_fp8(dr[r] * acc[ct][r]);
                } else {
                    ((ushort_t*)Yv)[(size_t)row * COLS + ch] = f2b(acc[ct][r]);
                }
            }
        }
    }
}

// ------- conv1 aggregation, half pass q: dense 64-ch fp8 table [n][64] (3.2MB, L2-resident).
//         wave per node; 4 rows/gather (16-lane groups x 4ch); csr shfl-broadcast + prefetch;
//         pre-scaled table -> pure sum; bias+relu; writes h bf16 half ----------
__global__ __launch_bounds__(256) void k_agg1h(const uchar_t* __restrict__ t1,  // fp8 [n][64] half
                                               const int* __restrict__ csr,
                                               const int* __restrict__ rowstart, const int* __restrict__ cnt,
                                               const float* __restrict__ dinv, const float* __restrict__ b1,
                                               uint* __restrict__ h, int n, int q) {
    int tid = threadIdx.x;
    int i = blockIdx.x * 4 + (tid >> 6);
    if (i >= n) return;
    int lane = tid & 63;
    int g = lane >> 4, cl = lane & 15;           // g: row group 0..3, cl: 4-ch group
    float a0 = 0.f, a1 = 0.f, a2 = 0.f, a3 = 0.f;
    if (g == 0) {                                // self loop: t1[i]
        uint v = *(const uint*)(t1 + ((size_t)i << 6) + cl * 4);
        f32x2 lo = fp8x2_lo(v), hi = fp8x2_hi(v);
        a0 = lo.x; a1 = lo.y; a2 = hi.x; a3 = hi.y;
    }
    int beg = rowstart[i], m = cnt[i];
    int j = 0;
    int c = (m >= 8) ? csr[beg + (lane & 7)] : 0;
    for (; j + 8 <= m; ) {
        int jn = j + 8;
        int cn = (jn + 8 <= m) ? csr[beg + jn + (lane & 7)] : 0;
        int s0 = __shfl(c, 0 + g);
        int s1 = __shfl(c, 4 + g);
        uint v0 = *(const uint*)(t1 + ((size_t)s0 << 6) + cl * 4);
        uint v1 = *(const uint*)(t1 + ((size_t)s1 << 6) + cl * 4);
        f32x2 p;
        p = fp8x2_lo(v0); a0 += p.x; a1 += p.y;  p = fp8x2_hi(v0); a2 += p.x; a3 += p.y;
        p = fp8x2_lo(v1); a0 += p.x; a1 += p.y;  p = fp8x2_hi(v1); a2 += p.x; a3 += p.y;
        c = cn; j = jn;
    }
    for (; j < m; j += 4) {
        int idx = j + g;
        if (idx < m) {
            int s = csr[beg + idx];
            uint v = *(const uint*)(t1 + ((size_t)s << 6) + cl * 4);
            f32x2 p;
            p = fp8x2_lo(v); a0 += p.x; a1 += p.y;
            p = fp8x2_hi(v); a2 += p.x; a3 += p.y;
        }
    }
    // combine the four row-groups
    a0 += __shfl_xor(a0, 16); a1 += __shfl_xor(a1, 16);
    a2 += __shfl_xor(a2, 16); a3 += __shfl_xor(a3, 16);
    a0 += __shfl_xor(a0, 32); a1 += __shfl_xor(a1, 32);
    a2 += __shfl_xor(a2, 32); a3 += __shfl_xor(a3, 32);
    if (lane < 16) {
        float di = dinv[i];
        float4 bb = ((const float4*)b1)[q * 16 + cl];
        float o0 = fmaxf(fmaf(di, a0, bb.x), 0.f);
        float o1 = fmaxf(fmaf(di, a1, bb.y), 0.f);
        float o2 = fmaxf(fmaf(di, a2, bb.z), 0.f);
        float o3 = fmaxf(fmaf(di, a3, bb.w), 0.f);
        uint2 pk;
        pk.x = (uint)f2b(o0) | ((uint)f2b(o1) << 16);
        pk.y = (uint)f2b(o2) | ((uint)f2b(o3) << 16);
        *(uint2*)&h[((size_t)i << 6) + q * 32 + cl * 2] = pk;
    }
}

// ---- conv2 aggregation: wave per node; 4 rows/gather; csr prefetch; pre-scaled [n][64] fp8
//      table; fused bias + log_softmax (4 ch/lane + 16-lane butterfly) ----
__global__ __launch_bounds__(256) void k_agg2(const uchar_t* __restrict__ t2,  // fp8 [n][64]
                                              const int* __restrict__ csr,
                                              const int* __restrict__ rowstart, const int* __restrict__ cnt,
                                              const float* __restrict__ dinv, const float* __restrict__ b2,
                                              float* __restrict__ out, int n) {
    int tid = threadIdx.x;
    int i = blockIdx.x * 4 + (tid >> 6);
    if (i >= n) return;
    int lane = tid & 63;
    int g = lane >> 4, cl = lane & 15;
    float a0 = 0.f, a1 = 0.f, a2 = 0.f, a3 = 0.f;
    if (g == 0) {                                // self loop: t2[i]
        uint v = *(const uint*)(t2 + ((size_t)i << 6) + cl * 4);
        f32x2 lo = fp8x2_lo(v), hi = fp8x2_hi(v);
        a0 = lo.x; a1 = lo.y; a2 = hi.x; a3 = hi.y;
    }
    int beg = rowstart[i], m = cnt[i];
    int j = 0;
    int c = (m >= 8) ? csr[beg + (lane & 7)] : 0;
    for (; j + 8 <= m; ) {
        int jn = j + 8;
        int cn = (jn + 8 <= m) ? csr[beg + jn + (lane & 7)] : 0;
        int s0 = __shfl(c, 0 + g);
        int s1 = __shfl(c, 4 + g);
        uint v0 = *(const uint*)(t2 + ((size_t)s0 << 6) + cl * 4);
        uint v1 = *(const uint*)(t2 + ((size_t)s1 << 6) + cl * 4);
        f32x2 p;
        p = fp8x2_lo(v0); a0 += p.x; a1 += p.y;  p = fp8x2_hi(v0); a2 += p.x; a3 += p.y;
        p = fp8x2_lo(v1); a0 += p.x; a1 += p.y;  p = fp8x2_hi(v1); a2 += p.x; a3 += p.y;
        c = cn; j = jn;
    }
    for (; j < m; j += 4) {
        int idx = j + g;
        if (idx < m) {
            int s = csr[beg + idx];
            uint v = *(const uint*)(t2 + ((size_t)s << 6) + cl * 4);
            f32x2 p;
            p = fp8x2_lo(v); a0 += p.x; a1 += p.y;
            p = fp8x2_hi(v); a2 += p.x; a3 += p.y;
        }
    }
    // combine the four row-groups
    a0 += __shfl_xor(a0, 16); a1 += __shfl_xor(a1, 16);
    a2 += __shfl_xor(a2, 16); a3 += __shfl_xor(a3, 16);
    a0 += __shfl_xor(a0, 32); a1 += __shfl_xor(a1, 32);
    a2 += __shfl_xor(a2, 32); a3 += __shfl_xor(a3, 32);
    float di = dinv[i];
    float4 bb = ((const float4*)b2)[cl];
    float o0 = fmaf(di, a0, bb.x);
    float o1 = fmaf(di, a1, bb.y);
    float o2 = fmaf(di, a2, bb.z);
    float o3 = fmaf(di, a3, bb.w);
    // log_softmax over 64 ch: 4 ch local + butterfly over the 16-lane group
    float mx = fmaxf(fmaxf(o0, o1), fmaxf(o2, o3));
    mx = fmaxf(mx, __shfl_xor(mx, 1));
    mx = fmaxf(mx, __shfl_xor(mx, 2));
    mx = fmaxf(mx, __shfl_xor(mx, 4));
    mx = fmaxf(mx, __shfl_xor(mx, 8));
    float s = expf(o0 - mx) + expf(o1 - mx) + expf(o2 - mx) + expf(o3 - mx);
    s += __shfl_xor(s, 1);
    s += __shfl_xor(s, 2);
    s += __shfl_xor(s, 4);
    s += __shfl_xor(s, 8);
    float ls = mx + logf(s);
    if (lane < 16) {
        float4 r = make_float4(o0 - ls, o1 - ls, o2 - ls, o3 - ls);
        *(float4*)&out[((size_t)i << 6) + cl * 4] = r;
    }
}

extern "C" void kernel_launch(void* const* d_in, const int* in_sizes, int n_in,
                              void* d_out, int out_size, void* d_ws, size_t ws_size,
                              hipStream_t stream) {
    const float* x  = (const float*)d_in[0];
    const int* eidx = (const int*)d_in[1];
    const float* W1 = (const float*)d_in[2];
    const float* b1 = (const float*)d_in[3];
    const float* W2 = (const float*)d_in[4];
    const float* b2 = (const float*)d_in[5];
    float* out = (float*)d_out;

    const int n = in_sizes[0] / 128;       // 50000
    const int e = in_sizes[1] / 2;         // 1,600,000
    const int* esrc = eidx;
    const int* edst = eidx + e;
    const int nbk = (n + (1 << BSH) - 1) >> BSH;   // 391 buckets

    // workspace carve-up (256B aligned)
    size_t off = 0;
    auto carve = [&](size_t bytes) {
        void* p = (char*)d_ws + off;
        off += (bytes + 255) & ~(size_t)255;
        return p;
    };
    uchar_t*  xW1  = (uchar_t*)carve((size_t)n * 128);        // fp8, pre-scaled, [2][n][64] halves
    ushort_t* h    = (ushort_t*)carve((size_t)n * 128 * 2);   // bf16 [n][128]
    uchar_t*  hW2  = (uchar_t*)carve((size_t)n * 64);         // fp8, pre-scaled, [n][64]
    ushort_t* W1t  = (ushort_t*)carve(128 * 128 * 2);
    ushort_t* W2t  = (ushort_t*)carve(64 * 128 * 2);
    int*   cnt     = (int*)carve((size_t)n * 4);
    float* dinv    = (float*)carve((size_t)n * 4);
    int*   rowstart= (int*)carve((size_t)n * 4);
    int*   bktcnt  = (int*)carve((size_t)nbk * 4);
    int*   bktoff  = (int*)carve((size_t)nbk * 4);
    uint*  bin     = (uint*)carve((size_t)nbk * CAP * 4);
    int*   csr     = (int*)carve((size_t)e * 4);
    (void)ws_size;

    const int nbBin  = (e + BIN_CHUNK - 1) / BIN_CHUNK;
    const int nbWave = (n + 3) / 4;                // 4 waves per 256-block
    const int nbGemm = (n + 63) / 64;              // 64 rows per block

    k_init<<<(nbk + 255) / 256, 256, 0, stream>>>(bktcnt, nbk);
    k_bin<<<nbBin, 256, 0, stream>>>(esrc, edst, bktcnt, bin, e, nbk);
    k_scanBkt<<<1, 512, 0, stream>>>(bktcnt, bktoff, nbk);
    k_bucket<<<nbk, 256, 0, stream>>>(bin, bktcnt, bktoff, rowstart, cnt, dinv, csr, n);
    k_cvtW<<<96, 256, 0, stream>>>(W1, W2, W1t, W2t);

    // conv1: xW1 = fp8(dinv * (x @ W1)) in two dense 64-ch halves; 2 L2-resident agg passes
    k_mgemm<128, false, true, true><<<nbGemm, 256, 0, stream>>>(x, W1t, dinv, xW1, n);
    for (int q = 0; q < 2; ++q)
        k_agg1h<<<nbWave, 256, 0, stream>>>(xW1 + (size_t)q * n * 64, csr, rowstart, cnt,
                                            dinv, b1, (uint*)h, n, q);

    // conv2: hW2 = fp8(dinv * (h @ W2)), MFMA; agg2 gathers the pre-scaled 3.2MB table
    k_mgemm<64, true, true, false><<<nbGemm, 256, 0, stream>>>(h, W2t, dinv, hW2, n);
    k_agg2<<<nbWave, 256, 0, stream>>>(hW2, csr, rowstart, cnt, dinv, b2, out, n);
}

// Round 13
// 138.144 us; speedup vs baseline: 1.1777x; 1.1777x over previous
//
#include <hip/hip_runtime.h>
#include <hip/hip_bf16.h>
#include <math.h>

// GCN 2-layer: x[N,128] @ W1[128,128] -> gather/scatter norm agg -> +b1,relu
//              -> @ W2[128,64] -> agg -> +b2 -> log_softmax
// N=50000, E=1,600,000 (+N self loops handled analytically)
// - GEMMs: bf16 MFMA (16x16x32), XOR-swizzled LDS, W pre-transposed to bf16.
// - Gather tables store PRE-SCALED messages t[s] = dinv[s]*(xW)[s] in fp8 e4m3
//   (monolithic [N][128] / [N][64] layouts — channel-splitting loses, 3x tested).
// - Multi-row gathers with csr shfl-broadcast + PREFETCH, unroll 16:
//   agg1 = 8 two-row gathers in flight; agg2 = 4 four-row gathers in flight.
// - Graph build with zero per-edge global atomics (LDS-histogram binning).

typedef unsigned int uint;
typedef unsigned short ushort_t;
typedef unsigned char uchar_t;
typedef __attribute__((ext_vector_type(8))) short bf16x8;
typedef __attribute__((ext_vector_type(4))) float f32x4;
typedef __attribute__((ext_vector_type(2))) float f32x2;

#define BSH 7                    // bucket shift: 128 nodes per bucket
#define NBMAX 400                // >= ceil(50000/128)=391
#define BIN_CHUNK 4096           // edges per k_bin block (391 blocks)
#define CAP 6144                 // bin capacity per bucket (expected 4092, sd ~64)

__device__ inline ushort_t f2b(float f) {
    uint u = __float_as_uint(f);
    return (ushort_t)((u + 0x7fffu + ((u >> 16) & 1u)) >> 16);   // RNE
}

// ---- fp8 e4m3fn encode (RNE) / decode: manual fallbacks ----
__device__ inline uchar_t f2e4m3_sw(float f) {
    float a = fabsf(f);
    a = fminf(a, 448.f);
    uint sign = (__float_as_uint(f) >> 24) & 0x80u;
    uint u = __float_as_uint(a);
    int e = (int)(u >> 23) - 127;
    uint code;
    if (e < -6) {
        float t = a * 512.0f;
        uint m = (uint)(t + 0.5f);
        code = (m > 7) ? 0x08u : m;
    } else {
        uint lsb = (u >> 20) & 1u;
        u += 0x0007FFFFu + lsb;
        e = (int)(u >> 23) - 127;
        if (e > 8) code = 0x7Eu;
        else code = ((uint)(e + 7) << 3) | ((u >> 20) & 7u);
    }
    return (uchar_t)(sign | code);
}
__device__ inline float e4m3_sw(uint c) {
    uint ef = (c >> 3) & 15u, m = c & 7u;
    float v = ef ? __uint_as_float(((ef + 120u) << 23) | (m << 20))
                 : (float)m * 0.001953125f;
    return (c & 0x80u) ? -v : v;
}

// ---- hw fp8 conversions (gfx940+; OCP e4m3fn on gfx950) with sw fallback ----
__device__ inline f32x2 fp8x2_lo(uint v) {            // decode bytes 0,1
#if __has_builtin(__builtin_amdgcn_cvt_pk_f32_fp8)
    return __builtin_amdgcn_cvt_pk_f32_fp8(v, false);
#else
    return (f32x2){e4m3_sw(v & 255u), e4m3_sw((v >> 8) & 255u)};
#endif
}
__device__ inline f32x2 fp8x2_hi(uint v) {            // decode bytes 2,3
#if __has_builtin(__builtin_amdgcn_cvt_pk_f32_fp8)
    return __builtin_amdgcn_cvt_pk_f32_fp8(v, true);
#else
    return (f32x2){e4m3_sw((v >> 16) & 255u), e4m3_sw((v >> 24) & 255u)};
#endif
}
__device__ inline uchar_t f32_fp8(float f) {          // encode (RNE)
#if __has_builtin(__builtin_amdgcn_cvt_pk_fp8_f32)
    return (uchar_t)(__builtin_amdgcn_cvt_pk_fp8_f32(f, f, 0u, false) & 0xffu);
#else
    return f2e4m3_sw(f);
#endif
}

// ---------------- init: zero bucket counters ----------------
__global__ __launch_bounds__(256) void k_init(int* __restrict__ bktcnt, int nbk) {
    int i = blockIdx.x * 256 + threadIdx.x;
    if (i < nbk) bktcnt[i] = 0;
}

// ---------------- bin: bucket edges by dst>>BSH (LDS hist; block-segment writes) ----------------
__global__ __launch_bounds__(256) void k_bin(const int* __restrict__ esrc, const int* __restrict__ edst,
                                             int* __restrict__ bktcnt, uint* __restrict__ bin,
                                             int e, int nbk) {
    __shared__ int hist[NBMAX];
    __shared__ int segbase[NBMAX];
    int tid = threadIdx.x;
    int b0 = blockIdx.x * BIN_CHUNK;
    int b1 = min(b0 + BIN_CHUNK, e);
    for (int i = tid; i < nbk; i += 256) hist[i] = 0;
    __syncthreads();
    for (int i = b0 + tid * 4; i < b1; i += 1024) {
        if (i + 4 <= b1) {
            int4 d = *(const int4*)&edst[i];
            atomicAdd(&hist[d.x >> BSH], 1);
            atomicAdd(&hist[d.y >> BSH], 1);
            atomicAdd(&hist[d.z >> BSH], 1);
            atomicAdd(&hist[d.w >> BSH], 1);
        } else {
            for (int j = i; j < b1; ++j) atomicAdd(&hist[edst[j] >> BSH], 1);
        }
    }
    __syncthreads();
    for (int b = tid; b < nbk; b += 256) {
        int c = hist[b];
        int gb = c ? atomicAdd(&bktcnt[b], c) : 0;
        segbase[b] = b * CAP + gb;
        hist[b] = 0;  // reuse as local cursor
    }
    __syncthreads();
    for (int i = b0 + tid * 4; i < b1; i += 1024) {
        if (i + 4 <= b1) {
            int4 d = *(const int4*)&edst[i];
            int4 s = *(const int4*)&esrc[i];
            int bx = d.x >> BSH, by = d.y >> BSH, bz = d.z >> BSH, bw = d.w >> BSH;
            int px = atomicAdd(&hist[bx], 1);
            int py = atomicAdd(&hist[by], 1);
            int pz = atomicAdd(&hist[bz], 1);
            int pw = atomicAdd(&hist[bw], 1);
            bin[segbase[bx] + px] = (uint)s.x | ((uint)(d.x & 127) << 17);
            bin[segbase[by] + py] = (uint)s.y | ((uint)(d.y & 127) << 17);
            bin[segbase[bz] + pz] = (uint)s.z | ((uint)(d.z & 127) << 17);
            bin[segbase[bw] + pw] = (uint)s.w | ((uint)(d.w & 127) << 17);
        } else {
            for (int j = i; j < b1; ++j) {
                int d = edst[j], s = esrc[j];
                int b = d >> BSH;
                int p = atomicAdd(&hist[b], 1);
                bin[segbase[b] + p] = (uint)s | ((uint)(d & 127) << 17);
            }
        }
    }
}

// ---------------- scan of 391 bucket counts -> bucket CSR bases (one block) ----------------
__global__ __launch_bounds__(512) void k_scanBkt(const int* __restrict__ bktcnt, int* __restrict__ bktoff,
                                                 int nbk) {
    int tid = threadIdx.x;
    int v = (tid < nbk) ? bktcnt[tid] : 0;
    int x = v;
    for (int off = 1; off < 64; off <<= 1) {
        int y = __shfl_up(x, off);
        if ((tid & 63) >= off) x += y;
    }
    __shared__ int wt[8];
    if ((tid & 63) == 63) wt[tid >> 6] = x;
    __syncthreads();
    int w = tid >> 6, woff = 0;
    for (int k = 0; k < w; ++k) woff += wt[k];
    if (tid < nbk) bktoff[tid] = x - v + woff;
}

// ---------------- per-bucket: count/scan/scatter inside an L2-resident window ----------------
__global__ __launch_bounds__(256) void k_bucket(const uint* __restrict__ bin, const int* __restrict__ bktcnt,
                                                const int* __restrict__ bktoff,
                                                int* __restrict__ rowstart, int* __restrict__ cnt,
                                                float* __restrict__ dinv, int* __restrict__ csr, int n) {
    __shared__ int lcnt[1 << BSH];
    __shared__ int cur[1 << BSH];
    __shared__ int wt[4];
    int b = blockIdx.x;
    int tid = threadIdx.x;
    int lo = b << BSH;
    int nl = min(1 << BSH, n - lo);
    int m = bktcnt[b];
    int base = b * CAP;
    int obase = bktoff[b];
    if (tid < (1 << BSH)) lcnt[tid] = 0;
    __syncthreads();
    for (int i = tid; i < m; i += 256) {
        uint v = bin[base + i];
        atomicAdd(&lcnt[v >> 17], 1);
    }
    __syncthreads();
    int v = (tid < (1 << BSH)) ? lcnt[tid] : 0;
    int x = v;
    for (int off = 1; off < 64; off <<= 1) {
        int y = __shfl_up(x, off);
        if ((tid & 63) >= off) x += y;
    }
    if ((tid & 63) == 63) wt[tid >> 6] = x;
    __syncthreads();
    int excl = x - v + ((tid >= 64 && tid < 128) ? wt[0] : 0);
    if (tid < nl) {
        int node = lo + tid;
        rowstart[node] = obase + excl;
        cnt[node] = v;
        dinv[node] = rsqrtf((float)(v + 1));   // +1 self loop
        cur[tid] = obase + excl;
    }
    __syncthreads();
    for (int i = tid; i < m; i += 256) {
        uint en = bin[base + i];
        int dl = en >> 17;
        int p = atomicAdd(&cur[dl], 1);
        csr[p] = (int)(en & 0x1FFFFu);
    }
}

// ---------------- one-time weight transpose+cvt: W1[128x128]->W1t[n][k], W2[128x64]->W2t[n][k] ----
__global__ __launch_bounds__(256) void k_cvtW(const float* __restrict__ W1, const float* __restrict__ W2,
                                              ushort_t* __restrict__ W1t, ushort_t* __restrict__ W2t) {
    int i = blockIdx.x * 256 + threadIdx.x;
    if (i < 16384) {
        int k = i >> 7, nn = i & 127;
        W1t[nn * 128 + k] = f2b(W1[k * 128 + nn]);
    } else if (i < 16384 + 8192) {
        int j = i - 16384;
        int k = j >> 6, nn = j & 63;
        W2t[nn * 128 + k] = f2b(W2[k * 64 + nn]);
    }
}

// ---------------- MFMA bf16 GEMM: Y[n,COLS] = dinv[row] * (X[n,128] @ W[128,COLS]) -------------
// BR=64 rows/block, 4 waves x 16 rows; full K=128 in LDS; Wt = W^T[n][k] bf16.
// OUTFP8: emit fp8 e4m3 of the dinv-prescaled value (gather-table form).
template <int COLS, bool XBF16, bool OUTFP8>
__global__ __launch_bounds__(256) void k_mgemm(const void* __restrict__ Xv, const ushort_t* __restrict__ Wt,
                                               const float* __restrict__ dinv,
                                               void* __restrict__ Yv, int nrows) {
    constexpr int NT = COLS / 16;                  // col tiles
    __shared__ ushort_t lsX[64 * 128];             // 16KB
    __shared__ ushort_t lsW[COLS * 128];           // 32KB (COLS=128) / 16KB (64)
    int tid = threadIdx.x;
    int rbase = blockIdx.x * 64;

    // stage X tile: 8192 bf16, 8 per thread-iter, swizzled 16B stores
#pragma unroll
    for (int it = 0; it < 4; ++it) {
        int idx = (tid + it * 256) * 8;
        int r = idx >> 7, c = idx & 127;
        int grow = rbase + r;
        uint4 pv = make_uint4(0, 0, 0, 0);
        if (grow < nrows) {
            if (XBF16) {
                pv = *(const uint4*)((const ushort_t*)Xv + (size_t)grow * 128 + c);
            } else {
                const float* xp = (const float*)Xv + (size_t)grow * 128 + c;
                float4 a = *(const float4*)xp;
                float4 b = *(const float4*)(xp + 4);
                pv.x = (uint)f2b(a.x) | ((uint)f2b(a.y) << 16);
                pv.y = (uint)f2b(a.z) | ((uint)f2b(a.w) << 16);
                pv.z = (uint)f2b(b.x) | ((uint)f2b(b.y) << 16);
                pv.w = (uint)f2b(b.z) | ((uint)f2b(b.w) << 16);
            }
        }
        int boff = (r * 256 + c * 2) ^ ((r & 7) << 4);
        *(uint4*)((char*)lsX + boff) = pv;
    }
    // stage W^T: COLS*128 bf16 contiguous from global, swizzled
#pragma unroll
    for (int it = 0; it < NT; ++it) {
        int idx = (tid + it * 256) * 8;
        int nr = idx >> 7, k = idx & 127;
        uint4 v = *(const uint4*)&Wt[nr * 128 + k];
        int boff = (nr * 256 + k * 2) ^ ((nr & 7) << 4);
        *(uint4*)((char*)lsW + boff) = v;
    }
    __syncthreads();

    int w = tid >> 6, l = tid & 63;
    int lr = l & 15, lg = l >> 4;
    int xrow = w * 16 + lr;
    bf16x8 a[4];
#pragma unroll
    for (int ks = 0; ks < 4; ++ks) {
        int boff = (xrow * 256 + (ks * 32 + lg * 8) * 2) ^ ((xrow & 7) << 4);
        a[ks] = *(const bf16x8*)((const char*)lsX + boff);
    }
    f32x4 acc[NT];
#pragma unroll
    for (int ct = 0; ct < NT; ++ct) {
        acc[ct] = (f32x4){0.f, 0.f, 0.f, 0.f};
#pragma unroll
        for (int ks = 0; ks < 4; ++ks) {
            int wrow = ct * 16 + lr;
            int boff = (wrow * 256 + (ks * 32 + lg * 8) * 2) ^ ((wrow & 7) << 4);
            bf16x8 b = *(const bf16x8*)((const char*)lsW + boff);
            acc[ct] = __builtin_amdgcn_mfma_f32_16x16x32_bf16(a[ks], b, acc[ct], 0, 0, 0);
        }
    }
    // per-output-row dinv prescale (rows depend on r only)
    float dr[4];
#pragma unroll
    for (int r = 0; r < 4; ++r) {
        int row = rbase + w * 16 + lg * 4 + r;
        dr[r] = (OUTFP8 && row < nrows) ? dinv[row] : 1.f;
    }
    // C-write: row = rbase + w*16 + lg*4 + r, ch = ct*16 + lr  [m89 layout]
#pragma unroll
    for (int ct = 0; ct < NT; ++ct) {
        int ch = ct * 16 + lr;
#pragma unroll
        for (int r = 0; r < 4; ++r) {
            int row = rbase + w * 16 + lg * 4 + r;
            if (row < nrows) {
                if (OUTFP8) ((uchar_t*)Yv)[(size_t)row * COLS + ch] = f32_fp8(dr[r] * acc[ct][r]);
                else        ((ushort_t*)Yv)[(size_t)row * COLS + ch] = f2b(acc[ct][r]);
            }
        }
    }
}

// ------- conv1 aggregation: wave per node; 2 rows/gather (half-wave x 4 fp8 ch/lane);
//         unroll 16 + csr prefetch -> 8 gathers in flight; pre-scaled table;
//         bias+relu; h out bf16 [n][128] ----------
__global__ __launch_bounds__(256) void k_agg1(const uchar_t* __restrict__ t1,  // fp8 [n][128]
                                              const int* __restrict__ csr,
                                              const int* __restrict__ rowstart, const int* __restrict__ cnt,
                                              const float* __restrict__ dinv, const float* __restrict__ b1,
                                              uint* __restrict__ h, int n) {
    int tid = threadIdx.x;
    int i = blockIdx.x * 4 + (tid >> 6);
    if (i >= n) return;
    int lane = tid & 63;
    int half = lane >> 5, cl = lane & 31;        // cl: 4-channel group 0..31
    float a0 = 0.f, a1 = 0.f, a2 = 0.f, a3 = 0.f;
    if (half == 0) {                             // self loop: t1[i]
        uint v = *(const uint*)(t1 + ((size_t)i << 7) + cl * 4);
        f32x2 lo = fp8x2_lo(v), hi = fp8x2_hi(v);
        a0 = lo.x; a1 = lo.y; a2 = hi.x; a3 = hi.y;
    }
    int beg = rowstart[i], m = cnt[i];
    int j = 0;
    int c = (m >= 16) ? csr[beg + (lane & 15)] : 0;
    for (; j + 16 <= m; ) {
        int jn = j + 16;
        int cn = (jn + 16 <= m) ? csr[beg + jn + (lane & 15)] : 0;
        int s0 = __shfl(c, 0 + half),  s1 = __shfl(c, 2 + half);
        int s2 = __shfl(c, 4 + half),  s3 = __shfl(c, 6 + half);
        int s4 = __shfl(c, 8 + half),  s5 = __shfl(c, 10 + half);
        int s6 = __shfl(c, 12 + half), s7 = __shfl(c, 14 + half);
        uint v0 = *(const uint*)(t1 + ((size_t)s0 << 7) + cl * 4);
        uint v1 = *(const uint*)(t1 + ((size_t)s1 << 7) + cl * 4);
        uint v2 = *(const uint*)(t1 + ((size_t)s2 << 7) + cl * 4);
        uint v3 = *(const uint*)(t1 + ((size_t)s3 << 7) + cl * 4);
        uint v4 = *(const uint*)(t1 + ((size_t)s4 << 7) + cl * 4);
        uint v5 = *(const uint*)(t1 + ((size_t)s5 << 7) + cl * 4);
        uint v6 = *(const uint*)(t1 + ((size_t)s6 << 7) + cl * 4);
        uint v7 = *(const uint*)(t1 + ((size_t)s7 << 7) + cl * 4);
        f32x2 p;
        p = fp8x2_lo(v0); a0 += p.x; a1 += p.y;  p = fp8x2_hi(v0); a2 += p.x; a3 += p.y;
        p = fp8x2_lo(v1); a0 += p.x; a1 += p.y;  p = fp8x2_hi(v1); a2 += p.x; a3 += p.y;
        p = fp8x2_lo(v2); a0 += p.x; a1 += p.y;  p = fp8x2_hi(v2); a2 += p.x; a3 += p.y;
        p = fp8x2_lo(v3); a0 += p.x; a1 += p.y;  p = fp8x2_hi(v3); a2 += p.x; a3 += p.y;
        p = fp8x2_lo(v4); a0 += p.x; a1 += p.y;  p = fp8x2_hi(v4); a2 += p.x; a3 += p.y;
        p = fp8x2_lo(v5); a0 += p.x; a1 += p.y;  p = fp8x2_hi(v5); a2 += p.x; a3 += p.y;
        p = fp8x2_lo(v6); a0 += p.x; a1 += p.y;  p = fp8x2_hi(v6); a2 += p.x; a3 += p.y;
        p = fp8x2_lo(v7); a0 += p.x; a1 += p.y;  p = fp8x2_hi(v7); a2 += p.x; a3 += p.y;
        c = cn; j = jn;
    }
    if (j + 8 <= m) {
        int c8 = csr[beg + j + (lane & 7)];
        int s0 = __shfl(c8, 0 + half), s1 = __shfl(c8, 2 + half);
        int s2 = __shfl(c8, 4 + half), s3 = __shfl(c8, 6 + half);
        uint v0 = *(const uint*)(t1 + ((size_t)s0 << 7) + cl * 4);
        uint v1 = *(const uint*)(t1 + ((size_t)s1 << 7) + cl * 4);
        uint v2 = *(const uint*)(t1 + ((size_t)s2 << 7) + cl * 4);
        uint v3 = *(const uint*)(t1 + ((size_t)s3 << 7) + cl * 4);
        f32x2 p;
        p = fp8x2_lo(v0); a0 += p.x; a1 += p.y;  p = fp8x2_hi(v0); a2 += p.x; a3 += p.y;
        p = fp8x2_lo(v1); a0 += p.x; a1 += p.y;  p = fp8x2_hi(v1); a2 += p.x; a3 += p.y;
        p = fp8x2_lo(v2); a0 += p.x; a1 += p.y;  p = fp8x2_hi(v2); a2 += p.x; a3 += p.y;
        p = fp8x2_lo(v3); a0 += p.x; a1 += p.y;  p = fp8x2_hi(v3); a2 += p.x; a3 += p.y;
        j += 8;
    }
    for (; j < m; j += 2) {
        int idx = j + half;
        if (idx < m) {
            int s = csr[beg + idx];
            uint v = *(const uint*)(t1 + ((size_t)s << 7) + cl * 4);
            f32x2 p;
            p = fp8x2_lo(v); a0 += p.x; a1 += p.y;
            p = fp8x2_hi(v); a2 += p.x; a3 += p.y;
        }
    }
    // combine the two halves
    a0 += __shfl_xor(a0, 32); a1 += __shfl_xor(a1, 32);
    a2 += __shfl_xor(a2, 32); a3 += __shfl_xor(a3, 32);
    float di = dinv[i];
    float4 bb = ((const float4*)b1)[cl];
    float o0 = fmaxf(fmaf(di, a0, bb.x), 0.f);
    float o1 = fmaxf(fmaf(di, a1, bb.y), 0.f);
    float o2 = fmaxf(fmaf(di, a2, bb.z), 0.f);
    float o3 = fmaxf(fmaf(di, a3, bb.w), 0.f);
    if (half == 0) {
        uint2 pk;
        pk.x = (uint)f2b(o0) | ((uint)f2b(o1) << 16);
        pk.y = (uint)f2b(o2) | ((uint)f2b(o3) << 16);
        *(uint2*)&h[((size_t)i << 6) + cl * 2] = pk;
    }
}

// ---- conv2 aggregation: wave per node; 4 rows/gather (16-lane groups x 4 fp8 ch/lane);
//      unroll 16 + csr prefetch -> 4 gathers in flight; pre-scaled [n][64] table;
//      fused bias + log_softmax ----
__global__ __launch_bounds__(256) void k_agg2(const uchar_t* __restrict__ t2,  // fp8 [n][64]
                                              const int* __restrict__ csr,
                                              const int* __restrict__ rowstart, const int* __restrict__ cnt,
                                              const float* __restrict__ dinv, const float* __restrict__ b2,
                                              float* __restrict__ out, int n) {
    int tid = threadIdx.x;
    int i = blockIdx.x * 4 + (tid >> 6);
    if (i >= n) return;
    int lane = tid & 63;
    int g = lane >> 4, cl = lane & 15;           // cl: 4-channel group 0..15
    float a0 = 0.f, a1 = 0.f, a2 = 0.f, a3 = 0.f;
    if (g == 0) {                                // self loop: t2[i]
        uint v = *(const uint*)(t2 + ((size_t)i << 6) + cl * 4);
        f32x2 lo = fp8x2_lo(v), hi = fp8x2_hi(v);
        a0 = lo.x; a1 = lo.y; a2 = hi.x; a3 = hi.y;
    }
    int beg = rowstart[i], m = cnt[i];
    int j = 0;
    int c = (m >= 16) ? csr[beg + (lane & 15)] : 0;
    for (; j + 16 <= m; ) {
        int jn = j + 16;
        int cn = (jn + 16 <= m) ? csr[beg + jn + (lane & 15)] : 0;
        int s0 = __shfl(c, 0 + g),  s1 = __shfl(c, 4 + g);
        int s2 = __shfl(c, 8 + g),  s3 = __shfl(c, 12 + g);
        uint v0 = *(const uint*)(t2 + ((size_t)s0 << 6) + cl * 4);
        uint v1 = *(const uint*)(t2 + ((size_t)s1 << 6) + cl * 4);
        uint v2 = *(const uint*)(t2 + ((size_t)s2 << 6) + cl * 4);
        uint v3 = *(const uint*)(t2 + ((size_t)s3 << 6) + cl * 4);
        f32x2 p;
        p = fp8x2_lo(v0); a0 += p.x; a1 += p.y;  p = fp8x2_hi(v0); a2 += p.x; a3 += p.y;
        p = fp8x2_lo(v1); a0 += p.x; a1 += p.y;  p = fp8x2_hi(v1); a2 += p.x; a3 += p.y;
        p = fp8x2_lo(v2); a0 += p.x; a1 += p.y;  p = fp8x2_hi(v2); a2 += p.x; a3 += p.y;
        p = fp8x2_lo(v3); a0 += p.x; a1 += p.y;  p = fp8x2_hi(v3); a2 += p.x; a3 += p.y;
        c = cn; j = jn;
    }
    if (j + 8 <= m) {
        int c8 = csr[beg + j + (lane & 7)];
        int s0 = __shfl(c8, 0 + g), s1 = __shfl(c8, 4 + g);
        uint v0 = *(const uint*)(t2 + ((size_t)s0 << 6) + cl * 4);
        uint v1 = *(const uint*)(t2 + ((size_t)s1 << 6) + cl * 4);
        f32x2 p;
        p = fp8x2_lo(v0); a0 += p.x; a1 += p.y;  p = fp8x2_hi(v0); a2 += p.x; a3 += p.y;
        p = fp8x2_lo(v1); a0 += p.x; a1 += p.y;  p = fp8x2_hi(v1); a2 += p.x; a3 += p.y;
        j += 8;
    }
    for (; j < m; j += 4) {
        int idx = j + g;
        if (idx < m) {
            int s = csr[beg + idx];
            uint v = *(const uint*)(t2 + ((size_t)s << 6) + cl * 4);
            f32x2 p;
            p = fp8x2_lo(v); a0 += p.x; a1 += p.y;
            p = fp8x2_hi(v); a2 += p.x; a3 += p.y;
        }
    }
    // combine the four quarter-groups
    a0 += __shfl_xor(a0, 16); a1 += __shfl_xor(a1, 16);
    a2 += __shfl_xor(a2, 16); a3 += __shfl_xor(a3, 16);
    a0 += __shfl_xor(a0, 32); a1 += __shfl_xor(a1, 32);
    a2 += __shfl_xor(a2, 32); a3 += __shfl_xor(a3, 32);
    float di = dinv[i];
    float4 bb = ((const float4*)b2)[cl];
    float o0 = fmaf(di, a0, bb.x);
    float o1 = fmaf(di, a1, bb.y);
    float o2 = fmaf(di, a2, bb.z);
    float o3 = fmaf(di, a3, bb.w);
    // log_softmax over 64 ch: 4 ch local + butterfly over the 16-lane group
    float mx = fmaxf(fmaxf(o0, o1), fmaxf(o2, o3));
    mx = fmaxf(mx, __shfl_xor(mx, 1));
    mx = fmaxf(mx, __shfl_xor(mx, 2));
    mx = fmaxf(mx, __shfl_xor(mx, 4));
    mx = fmaxf(mx, __shfl_xor(mx, 8));
    float s = expf(o0 - mx) + expf(o1 - mx) + expf(o2 - mx) + expf(o3 - mx);
    s += __shfl_xor(s, 1);
    s += __shfl_xor(s, 2);
    s += __shfl_xor(s, 4);
    s += __shfl_xor(s, 8);
    float ls = mx + logf(s);
    if (lane < 16) {
        float4 r = make_float4(o0 - ls, o1 - ls, o2 - ls, o3 - ls);
        *(float4*)&out[((size_t)i << 6) + cl * 4] = r;
    }
}

extern "C" void kernel_launch(void* const* d_in, const int* in_sizes, int n_in,
                              void* d_out, int out_size, void* d_ws, size_t ws_size,
                              hipStream_t stream) {
    const float* x  = (const float*)d_in[0];
    const int* eidx = (const int*)d_in[1];
    const float* W1 = (const float*)d_in[2];
    const float* b1 = (const float*)d_in[3];
    const float* W2 = (const float*)d_in[4];
    const float* b2 = (const float*)d_in[5];
    float* out = (float*)d_out;

    const int n = in_sizes[0] / 128;       // 50000
    const int e = in_sizes[1] / 2;         // 1,600,000
    const int* esrc = eidx;
    const int* edst = eidx + e;
    const int nbk = (n + (1 << BSH) - 1) >> BSH;   // 391 buckets

    // workspace carve-up (256B aligned)
    size_t off = 0;
    auto carve = [&](size_t bytes) {
        void* p = (char*)d_ws + off;
        off += (bytes + 255) & ~(size_t)255;
        return p;
    };
    uchar_t*  xW1  = (uchar_t*)carve((size_t)n * 128);        // fp8 e4m3, pre-scaled by dinv
    ushort_t* h    = (ushort_t*)carve((size_t)n * 128 * 2);   // bf16
    uchar_t*  hW2  = (uchar_t*)carve((size_t)n * 64);         // fp8 e4m3, pre-scaled by dinv
    ushort_t* W1t  = (ushort_t*)carve(128 * 128 * 2);
    ushort_t* W2t  = (ushort_t*)carve(64 * 128 * 2);
    int*   cnt     = (int*)carve((size_t)n * 4);
    float* dinv    = (float*)carve((size_t)n * 4);
    int*   rowstart= (int*)carve((size_t)n * 4);
    int*   bktcnt  = (int*)carve((size_t)nbk * 4);
    int*   bktoff  = (int*)carve((size_t)nbk * 4);
    uint*  bin     = (uint*)carve((size_t)nbk * CAP * 4);
    int*   csr     = (int*)carve((size_t)e * 4);
    (void)ws_size;

    const int nbBin  = (e + BIN_CHUNK - 1) / BIN_CHUNK;
    const int nbWave = (n + 3) / 4;                // 4 waves per 256-block
    const int nbGemm = (n + 63) / 64;              // 64 rows per block

    k_init<<<(nbk + 255) / 256, 256, 0, stream>>>(bktcnt, nbk);
    k_bin<<<nbBin, 256, 0, stream>>>(esrc, edst, bktcnt, bin, e, nbk);
    k_scanBkt<<<1, 512, 0, stream>>>(bktcnt, bktoff, nbk);
    k_bucket<<<nbk, 256, 0, stream>>>(bin, bktcnt, bktoff, rowstart, cnt, dinv, csr, n);
    k_cvtW<<<96, 256, 0, stream>>>(W1, W2, W1t, W2t);

    // conv1: xW1 = fp8(dinv * (x @ W1)), MFMA; agg1 gathers the pre-scaled table
    k_mgemm<128, false, true><<<nbGemm, 256, 0, stream>>>(x, W1t, dinv, xW1, n);
    k_agg1<<<nbWave, 256, 0, stream>>>(xW1, csr, rowstart, cnt, dinv, b1, (uint*)h, n);

    // conv2: hW2 = fp8(dinv * (h @ W2)), MFMA; agg2 gathers the pre-scaled table
    k_mgemm<64, true, true><<<nbGemm, 256, 0, stream>>>(h, W2t, dinv, hW2, n);
    k_agg2<<<nbWave, 256, 0, stream>>>(hW2, csr, rowstart, cnt, dinv, b2, out, n);
}

// Round 14
// 134.141 us; speedup vs baseline: 1.2128x; 1.0298x over previous
//
#include <hip/hip_runtime.h>
#include <hip/hip_bf16.h>
#include <math.h>

// GCN 2-layer: x[N,128] @ W1[128,128] -> gather/scatter norm agg -> +b1,relu
//              -> @ W2[128,64] -> agg -> +b2 -> log_softmax
// N=50000, E=1,600,000 (+N self loops handled analytically)
// - GEMMs: bf16 MFMA (16x16x32), XOR-swizzled LDS, W pre-transposed to bf16.
// - Gather tables store PRE-SCALED messages t[s] = dinv[s]*(xW)[s] in fp8 e4m3
//   (monolithic layouts; channel-splitting loses, 3x tested).
// - Multi-row gathers with csr shfl-broadcast + prefetch, unroll 16.
// - 7-dispatch pipeline: prep -> bin -> bucket(inline scan) -> gemm1 -> agg1
//   -> gemm2 -> agg2(fused softmax).

typedef unsigned int uint;
typedef unsigned short ushort_t;
typedef unsigned char uchar_t;
typedef __attribute__((ext_vector_type(8))) short bf16x8;
typedef __attribute__((ext_vector_type(4))) float f32x4;
typedef __attribute__((ext_vector_type(2))) float f32x2;

#define BSH 7                    // bucket shift: 128 nodes per bucket
#define NBMAX 400                // >= ceil(50000/128)=391
#define BIN_CHUNK 4096           // edges per k_bin block (391 blocks)
#define CAP 6144                 // bin capacity per bucket (expected 4092, sd ~64)

__device__ inline ushort_t f2b(float f) {
    uint u = __float_as_uint(f);
    return (ushort_t)((u + 0x7fffu + ((u >> 16) & 1u)) >> 16);   // RNE
}

// ---- fp8 e4m3fn encode (RNE) / decode: manual fallbacks ----
__device__ inline uchar_t f2e4m3_sw(float f) {
    float a = fabsf(f);
    a = fminf(a, 448.f);
    uint sign = (__float_as_uint(f) >> 24) & 0x80u;
    uint u = __float_as_uint(a);
    int e = (int)(u >> 23) - 127;
    uint code;
    if (e < -6) {
        float t = a * 512.0f;
        uint m = (uint)(t + 0.5f);
        code = (m > 7) ? 0x08u : m;
    } else {
        uint lsb = (u >> 20) & 1u;
        u += 0x0007FFFFu + lsb;
        e = (int)(u >> 23) - 127;
        if (e > 8) code = 0x7Eu;
        else code = ((uint)(e + 7) << 3) | ((u >> 20) & 7u);
    }
    return (uchar_t)(sign | code);
}
__device__ inline float e4m3_sw(uint c) {
    uint ef = (c >> 3) & 15u, m = c & 7u;
    float v = ef ? __uint_as_float(((ef + 120u) << 23) | (m << 20))
                 : (float)m * 0.001953125f;
    return (c & 0x80u) ? -v : v;
}

// ---- hw fp8 conversions (gfx940+; OCP e4m3fn on gfx950) with sw fallback ----
__device__ inline f32x2 fp8x2_lo(uint v) {            // decode bytes 0,1
#if __has_builtin(__builtin_amdgcn_cvt_pk_f32_fp8)
    return __builtin_amdgcn_cvt_pk_f32_fp8(v, false);
#else
    return (f32x2){e4m3_sw(v & 255u), e4m3_sw((v >> 8) & 255u)};
#endif
}
__device__ inline f32x2 fp8x2_hi(uint v) {            // decode bytes 2,3
#if __has_builtin(__builtin_amdgcn_cvt_pk_f32_fp8)
    return __builtin_amdgcn_cvt_pk_f32_fp8(v, true);
#else
    return (f32x2){e4m3_sw((v >> 16) & 255u), e4m3_sw((v >> 24) & 255u)};
#endif
}
__device__ inline uchar_t f32_fp8(float f) {          // encode (RNE)
#if __has_builtin(__builtin_amdgcn_cvt_pk_fp8_f32)
    return (uchar_t)(__builtin_amdgcn_cvt_pk_fp8_f32(f, f, 0u, false) & 0xffu);
#else
    return f2e4m3_sw(f);
#endif
}

// ---------------- prep: zero bucket counters + weight transpose/cvt (one dispatch) -------------
__global__ __launch_bounds__(256) void k_prep(const float* __restrict__ W1, const float* __restrict__ W2,
                                              ushort_t* __restrict__ W1t, ushort_t* __restrict__ W2t,
                                              int* __restrict__ bktcnt, int nbk) {
    int i = blockIdx.x * 256 + threadIdx.x;
    if (i < 16384) {
        int k = i >> 7, nn = i & 127;
        W1t[nn * 128 + k] = f2b(W1[k * 128 + nn]);
    } else if (i < 16384 + 8192) {
        int j = i - 16384;
        int k = j >> 6, nn = j & 63;
        W2t[nn * 128 + k] = f2b(W2[k * 64 + nn]);
    } else if (i < 16384 + 8192 + nbk) {
        bktcnt[i - 16384 - 8192] = 0;
    }
}

// ---------------- bin: bucket edges by dst>>BSH (LDS hist; block-segment writes) ----------------
__global__ __launch_bounds__(256) void k_bin(const int* __restrict__ esrc, const int* __restrict__ edst,
                                             int* __restrict__ bktcnt, uint* __restrict__ bin,
                                             int e, int nbk) {
    __shared__ int hist[NBMAX];
    __shared__ int segbase[NBMAX];
    int tid = threadIdx.x;
    int b0 = blockIdx.x * BIN_CHUNK;
    int b1 = min(b0 + BIN_CHUNK, e);
    for (int i = tid; i < nbk; i += 256) hist[i] = 0;
    __syncthreads();
    for (int i = b0 + tid * 4; i < b1; i += 1024) {
        if (i + 4 <= b1) {
            int4 d = *(const int4*)&edst[i];
            atomicAdd(&hist[d.x >> BSH], 1);
            atomicAdd(&hist[d.y >> BSH], 1);
            atomicAdd(&hist[d.z >> BSH], 1);
            atomicAdd(&hist[d.w >> BSH], 1);
        } else {
            for (int j = i; j < b1; ++j) atomicAdd(&hist[edst[j] >> BSH], 1);
        }
    }
    __syncthreads();
    for (int b = tid; b < nbk; b += 256) {
        int c = hist[b];
        int gb = c ? atomicAdd(&bktcnt[b], c) : 0;
        segbase[b] = b * CAP + gb;
        hist[b] = 0;  // reuse as local cursor
    }
    __syncthreads();
    for (int i = b0 + tid * 4; i < b1; i += 1024) {
        if (i + 4 <= b1) {
            int4 d = *(const int4*)&edst[i];
            int4 s = *(const int4*)&esrc[i];
            int bx = d.x >> BSH, by = d.y >> BSH, bz = d.z >> BSH, bw = d.w >> BSH;
            int px = atomicAdd(&hist[bx], 1);
            int py = atomicAdd(&hist[by], 1);
            int pz = atomicAdd(&hist[bz], 1);
            int pw = atomicAdd(&hist[bw], 1);
            bin[segbase[bx] + px] = (uint)s.x | ((uint)(d.x & 127) << 17);
            bin[segbase[by] + py] = (uint)s.y | ((uint)(d.y & 127) << 17);
            bin[segbase[bz] + pz] = (uint)s.z | ((uint)(d.z & 127) << 17);
            bin[segbase[bw] + pw] = (uint)s.w | ((uint)(d.w & 127) << 17);
        } else {
            for (int j = i; j < b1; ++j) {
                int d = edst[j], s = esrc[j];
                int b = d >> BSH;
                int p = atomicAdd(&hist[b], 1);
                bin[segbase[b] + p] = (uint)s | ((uint)(d & 127) << 17);
            }
        }
    }
}

// ---------------- per-bucket: inline offset scan + count/scan/scatter (L2-resident window) ------
__global__ __launch_bounds__(256) void k_bucket(const uint* __restrict__ bin, const int* __restrict__ bktcnt,
                                                int* __restrict__ rowstart, int* __restrict__ cnt,
                                                float* __restrict__ dinv, int* __restrict__ csr, int n) {
    __shared__ int lcnt[1 << BSH];
    __shared__ int cur[1 << BSH];
    __shared__ int wt[4];
    __shared__ int wred[4];
    int b = blockIdx.x;
    int tid = threadIdx.x;
    int lo = b << BSH;
    int nl = min(1 << BSH, n - lo);
    int m = bktcnt[b];
    int base = b * CAP;
    // inline exclusive scan over previous buckets: obase = sum bktcnt[0..b)
    int partial = 0;
    for (int t = tid; t < b; t += 256) partial += bktcnt[t];
    for (int off = 32; off; off >>= 1) partial += __shfl_down(partial, off);
    if ((tid & 63) == 0) wred[tid >> 6] = partial;
    if (tid < (1 << BSH)) lcnt[tid] = 0;
    __syncthreads();
    int obase = wred[0] + wred[1] + wred[2] + wred[3];
    for (int i = tid; i < m; i += 256) {
        uint v = bin[base + i];
        atomicAdd(&lcnt[v >> 17], 1);
    }
    __syncthreads();
    int v = (tid < (1 << BSH)) ? lcnt[tid] : 0;
    int x = v;
    for (int off = 1; off < 64; off <<= 1) {
        int y = __shfl_up(x, off);
        if ((tid & 63) >= off) x += y;
    }
    if ((tid & 63) == 63) wt[tid >> 6] = x;
    __syncthreads();
    int excl = x - v + ((tid >= 64 && tid < 128) ? wt[0] : 0);
    if (tid < nl) {
        int node = lo + tid;
        rowstart[node] = obase + excl;
        cnt[node] = v;
        dinv[node] = rsqrtf((float)(v + 1));   // +1 self loop
        cur[tid] = obase + excl;
    }
    __syncthreads();
    for (int i = tid; i < m; i += 256) {
        uint en = bin[base + i];
        int dl = en >> 17;
        int p = atomicAdd(&cur[dl], 1);
        csr[p] = (int)(en & 0x1FFFFu);
    }
}

// ---------------- MFMA bf16 GEMM: Y[n,COLS] = dinv[row] * (X[n,128] @ W[128,COLS]) -------------
// BR=64 rows/block, 4 waves x 16 rows; full K=128 in LDS; Wt = W^T[n][k] bf16.
// OUTFP8: emit fp8 e4m3 of the dinv-prescaled value (gather-table form).
template <int COLS, bool XBF16, bool OUTFP8>
__global__ __launch_bounds__(256) void k_mgemm(const void* __restrict__ Xv, const ushort_t* __restrict__ Wt,
                                               const float* __restrict__ dinv,
                                               void* __restrict__ Yv, int nrows) {
    constexpr int NT = COLS / 16;                  // col tiles
    __shared__ ushort_t lsX[64 * 128];             // 16KB
    __shared__ ushort_t lsW[COLS * 128];           // 32KB (COLS=128) / 16KB (64)
    int tid = threadIdx.x;
    int rbase = blockIdx.x * 64;

    // stage X tile: 8192 bf16, 8 per thread-iter, swizzled 16B stores
#pragma unroll
    for (int it = 0; it < 4; ++it) {
        int idx = (tid + it * 256) * 8;
        int r = idx >> 7, c = idx & 127;
        int grow = rbase + r;
        uint4 pv = make_uint4(0, 0, 0, 0);
        if (grow < nrows) {
            if (XBF16) {
                pv = *(const uint4*)((const ushort_t*)Xv + (size_t)grow * 128 + c);
            } else {
                const float* xp = (const float*)Xv + (size_t)grow * 128 + c;
                float4 a = *(const float4*)xp;
                float4 b = *(const float4*)(xp + 4);
                pv.x = (uint)f2b(a.x) | ((uint)f2b(a.y) << 16);
                pv.y = (uint)f2b(a.z) | ((uint)f2b(a.w) << 16);
                pv.z = (uint)f2b(b.x) | ((uint)f2b(b.y) << 16);
                pv.w = (uint)f2b(b.z) | ((uint)f2b(b.w) << 16);
            }
        }
        int boff = (r * 256 + c * 2) ^ ((r & 7) << 4);
        *(uint4*)((char*)lsX + boff) = pv;
    }
    // stage W^T: COLS*128 bf16 contiguous from global, swizzled
#pragma unroll
    for (int it = 0; it < NT; ++it) {
        int idx = (tid + it * 256) * 8;
        int nr = idx >> 7, k = idx & 127;
        uint4 v = *(const uint4*)&Wt[nr * 128 + k];
        int boff = (nr * 256 + k * 2) ^ ((nr & 7) << 4);
        *(uint4*)((char*)lsW + boff) = v;
    }
    __syncthreads();

    int w = tid >> 6, l = tid & 63;
    int lr = l & 15, lg = l >> 4;
    int xrow = w * 16 + lr;
    bf16x8 a[4];
#pragma unroll
    for (int ks = 0; ks < 4; ++ks) {
        int boff = (xrow * 256 + (ks * 32 + lg * 8) * 2) ^ ((xrow & 7) << 4);
        a[ks] = *(const bf16x8*)((const char*)lsX + boff);
    }
    f32x4 acc[NT];
#pragma unroll
    for (int ct = 0; ct < NT; ++ct) {
        acc[ct] = (f32x4){0.f, 0.f, 0.f, 0.f};
#pragma unroll
        for (int ks = 0; ks < 4; ++ks) {
            int wrow = ct * 16 + lr;
            int boff = (wrow * 256 + (ks * 32 + lg * 8) * 2) ^ ((wrow & 7) << 4);
            bf16x8 b = *(const bf16x8*)((const char*)lsW + boff);
            acc[ct] = __builtin_amdgcn_mfma_f32_16x16x32_bf16(a[ks], b, acc[ct], 0, 0, 0);
        }
    }
    // per-output-row dinv prescale (rows depend on r only)
    float dr[4];
#pragma unroll
    for (int r = 0; r < 4; ++r) {
        int row = rbase + w * 16 + lg * 4 + r;
        dr[r] = (OUTFP8 && row < nrows) ? dinv[row] : 1.f;
    }
    // C-write: row = rbase + w*16 + lg*4 + r, ch = ct*16 + lr  [m89 layout]
#pragma unroll
    for (int ct = 0; ct < NT; ++ct) {
        int ch = ct * 16 + lr;
#pragma unroll
        for (int r = 0; r < 4; ++r) {
            int row = rbase + w * 16 + lg * 4 + r;
            if (row < nrows) {
                if (OUTFP8) ((uchar_t*)Yv)[(size_t)row * COLS + ch] = f32_fp8(dr[r] * acc[ct][r]);
                else        ((ushort_t*)Yv)[(size_t)row * COLS + ch] = f2b(acc[ct][r]);
            }
        }
    }
}

// ------- conv1 aggregation: wave per node; 2 rows/gather (half-wave x 4 fp8 ch/lane);
//         unroll 16 + csr prefetch -> 8 gathers in flight; pre-scaled table;
//         bias+relu; h out bf16 [n][128] ----------
__global__ __launch_bounds__(256) void k_agg1(const uchar_t* __restrict__ t1,  // fp8 [n][128]
                                              const int* __restrict__ csr,
                                              const int* __restrict__ rowstart, const int* __restrict__ cnt,
                                              const float* __restrict__ dinv, const float* __restrict__ b1,
                                              uint* __restrict__ h, int n) {
    int tid = threadIdx.x;
    int i = blockIdx.x * 4 + (tid >> 6);
    if (i >= n) return;
    int lane = tid & 63;
    int half = lane >> 5, cl = lane & 31;        // cl: 4-channel group 0..31
    float a0 = 0.f, a1 = 0.f, a2 = 0.f, a3 = 0.f;
    if (half == 0) {                             // self loop: t1[i]
        uint v = *(const uint*)(t1 + ((size_t)i << 7) + cl * 4);
        f32x2 lo = fp8x2_lo(v), hi = fp8x2_hi(v);
        a0 = lo.x; a1 = lo.y; a2 = hi.x; a3 = hi.y;
    }
    int beg = rowstart[i], m = cnt[i];
    int j = 0;
    int c = (m >= 16) ? csr[beg + (lane & 15)] : 0;
    for (; j + 16 <= m; ) {
        int jn = j + 16;
        int cn = (jn + 16 <= m) ? csr[beg + jn + (lane & 15)] : 0;
        int s0 = __shfl(c, 0 + half),  s1 = __shfl(c, 2 + half);
        int s2 = __shfl(c, 4 + half),  s3 = __shfl(c, 6 + half);
        int s4 = __shfl(c, 8 + half),  s5 = __shfl(c, 10 + half);
        int s6 = __shfl(c, 12 + half), s7 = __shfl(c, 14 + half);
        uint v0 = *(const uint*)(t1 + ((size_t)s0 << 7) + cl * 4);
        uint v1 = *(const uint*)(t1 + ((size_t)s1 << 7) + cl * 4);
        uint v2 = *(const uint*)(t1 + ((size_t)s2 << 7) + cl * 4);
        uint v3 = *(const uint*)(t1 + ((size_t)s3 << 7) + cl * 4);
        uint v4 = *(const uint*)(t1 + ((size_t)s4 << 7) + cl * 4);
        uint v5 = *(const uint*)(t1 + ((size_t)s5 << 7) + cl * 4);
        uint v6 = *(const uint*)(t1 + ((size_t)s6 << 7) + cl * 4);
        uint v7 = *(const uint*)(t1 + ((size_t)s7 << 7) + cl * 4);
        f32x2 p;
        p = fp8x2_lo(v0); a0 += p.x; a1 += p.y;  p = fp8x2_hi(v0); a2 += p.x; a3 += p.y;
        p = fp8x2_lo(v1); a0 += p.x; a1 += p.y;  p = fp8x2_hi(v1); a2 += p.x; a3 += p.y;
        p = fp8x2_lo(v2); a0 += p.x; a1 += p.y;  p = fp8x2_hi(v2); a2 += p.x; a3 += p.y;
        p = fp8x2_lo(v3); a0 += p.x; a1 += p.y;  p = fp8x2_hi(v3); a2 += p.x; a3 += p.y;
        p = fp8x2_lo(v4); a0 += p.x; a1 += p.y;  p = fp8x2_hi(v4); a2 += p.x; a3 += p.y;
        p = fp8x2_lo(v5); a0 += p.x; a1 += p.y;  p = fp8x2_hi(v5); a2 += p.x; a3 += p.y;
        p = fp8x2_lo(v6); a0 += p.x; a1 += p.y;  p = fp8x2_hi(v6); a2 += p.x; a3 += p.y;
        p = fp8x2_lo(v7); a0 += p.x; a1 += p.y;  p = fp8x2_hi(v7); a2 += p.x; a3 += p.y;
        c = cn; j = jn;
    }
    if (j + 8 <= m) {
        int c8 = csr[beg + j + (lane & 7)];
        int s0 = __shfl(c8, 0 + half), s1 = __shfl(c8, 2 + half);
        int s2 = __shfl(c8, 4 + half), s3 = __shfl(c8, 6 + half);
        uint v0 = *(const uint*)(t1 + ((size_t)s0 << 7) + cl * 4);
        uint v1 = *(const uint*)(t1 + ((size_t)s1 << 7) + cl * 4);
        uint v2 = *(const uint*)(t1 + ((size_t)s2 << 7) + cl * 4);
        uint v3 = *(const uint*)(t1 + ((size_t)s3 << 7) + cl * 4);
        f32x2 p;
        p = fp8x2_lo(v0); a0 += p.x; a1 += p.y;  p = fp8x2_hi(v0); a2 += p.x; a3 += p.y;
        p = fp8x2_lo(v1); a0 += p.x; a1 += p.y;  p = fp8x2_hi(v1); a2 += p.x; a3 += p.y;
        p = fp8x2_lo(v2); a0 += p.x; a1 += p.y;  p = fp8x2_hi(v2); a2 += p.x; a3 += p.y;
        p = fp8x2_lo(v3); a0 += p.x; a1 += p.y;  p = fp8x2_hi(v3); a2 += p.x; a3 += p.y;
        j += 8;
    }
    for (; j < m; j += 2) {
        int idx = j + half;
        if (idx < m) {
            int s = csr[beg + idx];
            uint v = *(const uint*)(t1 + ((size_t)s << 7) + cl * 4);
            f32x2 p;
            p = fp8x2_lo(v); a0 += p.x; a1 += p.y;
            p = fp8x2_hi(v); a2 += p.x; a3 += p.y;
        }
    }
    // combine the two halves
    a0 += __shfl_xor(a0, 32); a1 += __shfl_xor(a1, 32);
    a2 += __shfl_xor(a2, 32); a3 += __shfl_xor(a3, 32);
    float di = dinv[i];
    float4 bb = ((const float4*)b1)[cl];
    float o0 = fmaxf(fmaf(di, a0, bb.x), 0.f);
    float o1 = fmaxf(fmaf(di, a1, bb.y), 0.f);
    float o2 = fmaxf(fmaf(di, a2, bb.z), 0.f);
    float o3 = fmaxf(fmaf(di, a3, bb.w), 0.f);
    if (half == 0) {
        uint2 pk;
        pk.x = (uint)f2b(o0) | ((uint)f2b(o1) << 16);
        pk.y = (uint)f2b(o2) | ((uint)f2b(o3) << 16);
        *(uint2*)&h[((size_t)i << 6) + cl * 2] = pk;
    }
}

// ---- conv2 aggregation: wave per node; 4 rows/gather (16-lane groups x 4 fp8 ch/lane);
//      unroll 16 + csr prefetch -> 4 gathers in flight; pre-scaled [n][64] table;
//      fused bias + log_softmax ----
__global__ __launch_bounds__(256) void k_agg2(const uchar_t* __restrict__ t2,  // fp8 [n][64]
                                              const int* __restrict__ csr,
                                              const int* __restrict__ rowstart, const int* __restrict__ cnt,
                                              const float* __restrict__ dinv, const float* __restrict__ b2,
                                              float* __restrict__ out, int n) {
    int tid = threadIdx.x;
    int i = blockIdx.x * 4 + (tid >> 6);
    if (i >= n) return;
    int lane = tid & 63;
    int g = lane >> 4, cl = lane & 15;           // cl: 4-channel group 0..15
    float a0 = 0.f, a1 = 0.f, a2 = 0.f, a3 = 0.f;
    if (g == 0) {                                // self loop: t2[i]
        uint v = *(const uint*)(t2 + ((size_t)i << 6) + cl * 4);
        f32x2 lo = fp8x2_lo(v), hi = fp8x2_hi(v);
        a0 = lo.x; a1 = lo.y; a2 = hi.x; a3 = hi.y;
    }
    int beg = rowstart[i], m = cnt[i];
    int j = 0;
    int c = (m >= 16) ? csr[beg + (lane & 15)] : 0;
    for (; j + 16 <= m; ) {
        int jn = j + 16;
        int cn = (jn + 16 <= m) ? csr[beg + jn + (lane & 15)] : 0;
        int s0 = __shfl(c, 0 + g),  s1 = __shfl(c, 4 + g);
        int s2 = __shfl(c, 8 + g),  s3 = __shfl(c, 12 + g);
        uint v0 = *(const uint*)(t2 + ((size_t)s0 << 6) + cl * 4);
        uint v1 = *(const uint*)(t2 + ((size_t)s1 << 6) + cl * 4);
        uint v2 = *(const uint*)(t2 + ((size_t)s2 << 6) + cl * 4);
        uint v3 = *(const uint*)(t2 + ((size_t)s3 << 6) + cl * 4);
        f32x2 p;
        p = fp8x2_lo(v0); a0 += p.x; a1 += p.y;  p = fp8x2_hi(v0); a2 += p.x; a3 += p.y;
        p = fp8x2_lo(v1); a0 += p.x; a1 += p.y;  p = fp8x2_hi(v1); a2 += p.x; a3 += p.y;
        p = fp8x2_lo(v2); a0 += p.x; a1 += p.y;  p = fp8x2_hi(v2); a2 += p.x; a3 += p.y;
        p = fp8x2_lo(v3); a0 += p.x; a1 += p.y;  p = fp8x2_hi(v3); a2 += p.x; a3 += p.y;
        c = cn; j = jn;
    }
    if (j + 8 <= m) {
        int c8 = csr[beg + j + (lane & 7)];
        int s0 = __shfl(c8, 0 + g), s1 = __shfl(c8, 4 + g);
        uint v0 = *(const uint*)(t2 + ((size_t)s0 << 6) + cl * 4);
        uint v1 = *(const uint*)(t2 + ((size_t)s1 << 6) + cl * 4);
        f32x2 p;
        p = fp8x2_lo(v0); a0 += p.x; a1 += p.y;  p = fp8x2_hi(v0); a2 += p.x; a3 += p.y;
        p = fp8x2_lo(v1); a0 += p.x; a1 += p.y;  p = fp8x2_hi(v1); a2 += p.x; a3 += p.y;
        j += 8;
    }
    for (; j < m; j += 4) {
        int idx = j + g;
        if (idx < m) {
            int s = csr[beg + idx];
            uint v = *(const uint*)(t2 + ((size_t)s << 6) + cl * 4);
            f32x2 p;
            p = fp8x2_lo(v); a0 += p.x; a1 += p.y;
            p = fp8x2_hi(v); a2 += p.x; a3 += p.y;
        }
    }
    // combine the four quarter-groups
    a0 += __shfl_xor(a0, 16); a1 += __shfl_xor(a1, 16);
    a2 += __shfl_xor(a2, 16); a3 += __shfl_xor(a3, 16);
    a0 += __shfl_xor(a0, 32); a1 += __shfl_xor(a1, 32);
    a2 += __shfl_xor(a2, 32); a3 += __shfl_xor(a3, 32);
    float di = dinv[i];
    float4 bb = ((const float4*)b2)[cl];
    float o0 = fmaf(di, a0, bb.x);
    float o1 = fmaf(di, a1, bb.y);
    float o2 = fmaf(di, a2, bb.z);
    float o3 = fmaf(di, a3, bb.w);
    // log_softmax over 64 ch: 4 ch local + butterfly over the 16-lane group
    float mx = fmaxf(fmaxf(o0, o1), fmaxf(o2, o3));
    mx = fmaxf(mx, __shfl_xor(mx, 1));
    mx = fmaxf(mx, __shfl_xor(mx, 2));
    mx = fmaxf(mx, __shfl_xor(mx, 4));
    mx = fmaxf(mx, __shfl_xor(mx, 8));
    float s = expf(o0 - mx) + expf(o1 - mx) + expf(o2 - mx) + expf(o3 - mx);
    s += __shfl_xor(s, 1);
    s += __shfl_xor(s, 2);
    s += __shfl_xor(s, 4);
    s += __shfl_xor(s, 8);
    float ls = mx + logf(s);
    if (lane < 16) {
        float4 r = make_float4(o0 - ls, o1 - ls, o2 - ls, o3 - ls);
        *(float4*)&out[((size_t)i << 6) + cl * 4] = r;
    }
}

extern "C" void kernel_launch(void* const* d_in, const int* in_sizes, int n_in,
                              void* d_out, int out_size, void* d_ws, size_t ws_size,
                              hipStream_t stream) {
    const float* x  = (const float*)d_in[0];
    const int* eidx = (const int*)d_in[1];
    const float* W1 = (const float*)d_in[2];
    const float* b1 = (const float*)d_in[3];
    const float* W2 = (const float*)d_in[4];
    const float* b2 = (const float*)d_in[5];
    float* out = (float*)d_out;

    const int n = in_sizes[0] / 128;       // 50000
    const int e = in_sizes[1] / 2;         // 1,600,000
    const int* esrc = eidx;
    const int* edst = eidx + e;
    const int nbk = (n + (1 << BSH) - 1) >> BSH;   // 391 buckets

    // workspace carve-up (256B aligned)
    size_t off = 0;
    auto carve = [&](size_t bytes) {
        void* p = (char*)d_ws + off;
        off += (bytes + 255) & ~(size_t)255;
        return p;
    };
    uchar_t*  xW1  = (uchar_t*)carve((size_t)n * 128);        // fp8 e4m3, pre-scaled by dinv
    ushort_t* h    = (ushort_t*)carve((size_t)n * 128 * 2);   // bf16
    uchar_t*  hW2  = (uchar_t*)carve((size_t)n * 64);         // fp8 e4m3, pre-scaled by dinv
    ushort_t* W1t  = (ushort_t*)carve(128 * 128 * 2);
    ushort_t* W2t  = (ushort_t*)carve(64 * 128 * 2);
    int*   cnt     = (int*)carve((size_t)n * 4);
    float* dinv    = (float*)carve((size_t)n * 4);
    int*   rowstart= (int*)carve((size_t)n * 4);
    int*   bktcnt  = (int*)carve((size_t)nbk * 4);
    uint*  bin     = (uint*)carve((size_t)nbk * CAP * 4);
    int*   csr     = (int*)carve((size_t)e * 4);
    (void)ws_size;

    const int nbBin  = (e + BIN_CHUNK - 1) / BIN_CHUNK;
    const int nbWave = (n + 3) / 4;                // 4 waves per 256-block
    const int nbGemm = (n + 63) / 64;              // 64 rows per block
    const int nbPrep = (16384 + 8192 + nbk + 255) / 256;

    // 7-dispatch pipeline
    k_prep<<<nbPrep, 256, 0, stream>>>(W1, W2, W1t, W2t, bktcnt, nbk);
    k_bin<<<nbBin, 256, 0, stream>>>(esrc, edst, bktcnt, bin, e, nbk);
    k_bucket<<<nbk, 256, 0, stream>>>(bin, bktcnt, rowstart, cnt, dinv, csr, n);

    // conv1: xW1 = fp8(dinv * (x @ W1)), MFMA; agg1 gathers the pre-scaled table
    k_mgemm<128, false, true><<<nbGemm, 256, 0, stream>>>(x, W1t, dinv, xW1, n);
    k_agg1<<<nbWave, 256, 0, stream>>>(xW1, csr, rowstart, cnt, dinv, b1, (uint*)h, n);

    // conv2: hW2 = fp8(dinv * (h @ W2)), MFMA; agg2 gathers the pre-scaled table
    k_mgemm<64, true, true><<<nbGemm, 256, 0, stream>>>(h, W2t, dinv, hW2, n);
    k_agg2<<<nbWave, 256, 0, stream>>>(hW2, csr, rowstart, cnt, dinv, b2, out, n);
}